// Round 7
// baseline (831.157 us; speedup 1.0000x reference)
//
#include <hip/hip_runtime.h>
#include <hip/hip_bf16.h>

// GAT 3-layer forward. N=50000, E=1.6M, H=4, D=32, C=47.
// Round 7: barrier-free wave-per-dst agg (no LDS, per-lane softmax norm,
// pipelined gathers) + el/er fused into the MFMA-gemm epilogue.
//
// ws: fs_bf[N*192 bf16] hbuf[N*192 f32] el[N*4] er[N*4] rowptr[N+1] cur[N]
//     col[E] bsum/boff[512] flag  => ~66 MB.

using bf16 = __hip_bfloat16;
typedef __attribute__((ext_vector_type(8))) short short8;
typedef __attribute__((ext_vector_type(4))) float floatx4;

static constexpr int NN = 50000;
static constexpr int H  = 4;

__device__ __forceinline__ float b2f(bf16 x) { return __bfloat162float(x); }
__device__ __forceinline__ float ldx(const void* p, size_t i, bool bf) {
    return bf ? __bfloat162float(((const bf16*)p)[i]) : ((const float*)p)[i];
}
__device__ __forceinline__ unsigned short f2b_bits(float v) {
    bf16 h = __float2bfloat16(v);
    return *reinterpret_cast<unsigned short*>(&h);
}
__device__ __forceinline__ unsigned short w_bits(const void* p, size_t i, bool bf) {
    if (bf) return ((const unsigned short*)p)[i];
    return f2b_bits(((const float*)p)[i]);
}
__device__ __forceinline__ float bl(unsigned u) { return __uint_as_float(u << 16); }
__device__ __forceinline__ float bh(unsigned u) { return __uint_as_float(u & 0xFFFF0000u); }
__device__ __forceinline__ float sel4(float4 v, int h) {
    float r = v.x;
    r = (h == 1) ? v.y : r;
    r = (h == 2) ? v.z : r;
    r = (h == 3) ? v.w : r;
    return r;
}

// ---------- dtype detection (bf16 vs fp32) ----------
__global__ void detect_k(const void* __restrict__ x, int* __restrict__ flag) {
    __shared__ int cnt;
    if (threadIdx.x == 0) cnt = 0;
    __syncthreads();
    const unsigned short* u = (const unsigned short*)x;
    unsigned short b = u[threadIdx.x * 2];
    int e = (b >> 7) & 0xFF;
    if (e >= 0x70 && e <= 0x8F) atomicAdd(&cnt, 1);
    __syncthreads();
    if (threadIdx.x == 0) *flag = (cnt > 128) ? 1 : 0;
}

__global__ void zero_i_k(int* __restrict__ p, int n) {
    int i = blockIdx.x * 256 + threadIdx.x;
    if (i < n) p[i] = 0;
}

// ---------- CSR build (by dst) ----------
__global__ void deg_k(const int* __restrict__ dst, int* __restrict__ deg, int E) {
    int e = blockIdx.x * 256 + threadIdx.x;
    if (e < E) atomicAdd(&deg[dst[e]], 1);
}

__global__ void scan1_k(const int* __restrict__ deg, int* __restrict__ rowptr,
                        int* __restrict__ bsum, int N) {
    __shared__ int buf[256];
    int tid = threadIdx.x, i = blockIdx.x * 256 + tid;
    int v = (i < N) ? deg[i] : 0;
    buf[tid] = v;
    __syncthreads();
    for (int off = 1; off < 256; off <<= 1) {
        int t = (tid >= off) ? buf[tid - off] : 0;
        __syncthreads();
        buf[tid] += t;
        __syncthreads();
    }
    if (i < N) rowptr[i] = buf[tid] - v;
    if (tid == 255) bsum[blockIdx.x] = buf[255];
}

__global__ void scan2_k(const int* __restrict__ bsum, int* __restrict__ boff, int nb) {
    __shared__ int buf[256];
    int tid = threadIdx.x;
    int v = (tid < nb) ? bsum[tid] : 0;
    buf[tid] = v;
    __syncthreads();
    for (int off = 1; off < 256; off <<= 1) {
        int t = (tid >= off) ? buf[tid - off] : 0;
        __syncthreads();
        buf[tid] += t;
        __syncthreads();
    }
    if (tid < nb) boff[tid] = buf[tid] - v;
}

__global__ void scan3_k(int* __restrict__ rowptr, const int* __restrict__ boff,
                        int N, int E) {
    int i = blockIdx.x * 256 + threadIdx.x;
    if (i < N) rowptr[i] += boff[blockIdx.x];
    if (i == 0) rowptr[N] = E;
}

__global__ void fill_k(const int* __restrict__ src, const int* __restrict__ dst,
                       const int* __restrict__ rowptr, int* __restrict__ cur,
                       int* __restrict__ col, int E) {
    int e = blockIdx.x * 256 + threadIdx.x;
    if (e >= E) return;
    int d = dst[e];
    int p = atomicAdd(&cur[d], 1);
    col[rowptr[d] + p] = src[e];
}

// ---------- MFMA GEMM + fused el/er epilogue ----------
// Block = 4 waves = 64 nodes. W^T in LDS bf16 (stride 136 shorts). K padded
// to 128. mfma_f32_16x16x32_bf16; D-layout: col=lane&15, row=(lane>>4)*4+reg.
// Epilogue computes el/er from fp32 accumulators via LDS reduce (reuses wlds).
template <int K, int M, int S, int HD, bool IN_EXT>
__global__ void __launch_bounds__(256) gemm_k(const void* __restrict__ in,
                                              const void* __restrict__ W,
                                              const void* __restrict__ al,
                                              const void* __restrict__ ar,
                                              bf16* __restrict__ fs,
                                              float* __restrict__ el,
                                              float* __restrict__ er,
                                              const int* __restrict__ flag, int N) {
    constexpr int KP  = 128;
    constexpr int CT  = S / 16;
    constexpr int WST = 136;
    __shared__ short wlds[S * WST];
    const bool bf = (*flag != 0);
    const int tid = threadIdx.x;

    // ---- stage W^T (c-major) into LDS, zero-pad k>=K and c>=M ----
    for (int idx = tid; idx < (KP / 2) * M; idx += 256) {
        int k2 = idx / M, c = idx % M;
        int k0 = 2 * k2;
        unsigned short u0 = (k0 < K)     ? w_bits(W, (size_t)k0 * M + c, bf)       : 0;
        unsigned short u1 = (k0 + 1 < K) ? w_bits(W, (size_t)(k0 + 1) * M + c, bf) : 0;
        *(unsigned*)&wlds[c * WST + 2 * k2] = (unsigned)u0 | ((unsigned)u1 << 16);
    }
    if (S > M) {
        for (int idx = tid; idx < (S - M) * (KP / 2); idx += 256) {
            int c = M + idx / (KP / 2);
            int k2 = idx % (KP / 2);
            *(unsigned*)&wlds[c * WST + 2 * k2] = 0u;
        }
    }
    __syncthreads();

    const int wave = tid >> 6, lane = tid & 63;
    const int q = lane >> 4, l16 = lane & 15;
    const int tile_base = blockIdx.x * 64 + wave * 16;
    const int node_a = tile_base + l16;

    floatx4 acc[CT] = {};

#pragma unroll
    for (int chunk = 0; chunk < 4; ++chunk) {
        const int kb = chunk * 32 + q * 8;
        short8 a;
        if (IN_EXT) {
#pragma unroll
            for (int j = 0; j < 8; ++j) {
                int k = kb + j;
                float v = (node_a < N && k < K) ? ldx(in, (size_t)node_a * K + k, bf) : 0.f;
                a[j] = (short)f2b_bits(v);
            }
        } else {
            const float* f = (const float*)in + (size_t)node_a * K + kb;
            float4 f0 = make_float4(0, 0, 0, 0), f1 = f0;
            if (node_a < N) { f0 = *(const float4*)f; f1 = *(const float4*)(f + 4); }
            a[0] = (short)f2b_bits(f0.x); a[1] = (short)f2b_bits(f0.y);
            a[2] = (short)f2b_bits(f0.z); a[3] = (short)f2b_bits(f0.w);
            a[4] = (short)f2b_bits(f1.x); a[5] = (short)f2b_bits(f1.y);
            a[6] = (short)f2b_bits(f1.z); a[7] = (short)f2b_bits(f1.w);
        }
#pragma unroll
        for (int ct = 0; ct < CT; ++ct) {
            const int c = ct * 16 + l16;
            short8 b = *(const short8*)&wlds[c * WST + kb];
            acc[ct] = __builtin_amdgcn_mfma_f32_16x16x32_bf16(a, b, acc[ct], 0, 0, 0);
        }
    }

    // ---- store fs ----
#pragma unroll
    for (int ct = 0; ct < CT; ++ct) {
        const int c = ct * 16 + l16;
#pragma unroll
        for (int r = 0; r < 4; ++r) {
            int node = tile_base + q * 4 + r;
            if (node < N) fs[(size_t)node * S + c] = __float2bfloat16(acc[ct][r]);
        }
    }

    // ---- fused el/er: el[n,h] = sum_c fs[n,c]*al[c] (fp32 acc) ----
    __syncthreads();                    // all wlds reads done; reuse as red buf
    float* red = (float*)wlds;          // 512 slots x 16 floats = 32 KB
    float elp[4][4] = {}, erp[4][4] = {};
#pragma unroll
    for (int ct = 0; ct < CT; ++ct) {
        const int c = ct * 16 + l16;
        float alc = (c < M) ? ldx(al, c, bf) : 0.f;
        float arc = (c < M) ? ldx(ar, c, bf) : 0.f;
        const int h = (c < M) ? (c / HD) : 3;
#pragma unroll
        for (int r = 0; r < 4; ++r) {
            float v = acc[ct][r];
#pragma unroll
            for (int h2 = 0; h2 < 4; ++h2) {
                elp[r][h2] += (h == h2) ? v * alc : 0.f;
                erp[r][h2] += (h == h2) ? v * arc : 0.f;
            }
        }
    }
#pragma unroll
    for (int r = 0; r < 4; ++r)
#pragma unroll
        for (int h2 = 0; h2 < 4; ++h2) {
            int slot = (wave * 128) + (q * 32) + (r * 8) + (h2 * 2);
            red[slot * 16 + l16] = elp[r][h2];
            red[(slot + 1) * 16 + l16] = erp[r][h2];
        }
    __syncthreads();
#pragma unroll
    for (int pass = 0; pass < 2; ++pass) {
        int slot = tid + pass * 256;
        float sum = 0.f;
#pragma unroll
        for (int j = 0; j < 16; ++j) sum += red[slot * 16 + j];
        int which = slot & 1;
        int h2 = (slot >> 1) & 3;
        int r  = (slot >> 3) & 3;
        int qq = (slot >> 5) & 3;
        int wv = slot >> 7;
        int node = blockIdx.x * 64 + wv * 16 + qq * 4 + r;
        if (node < N) {
            if (which == 0) el[(size_t)node * 4 + h2] = sum;
            else            er[(size_t)node * 4 + h2] = sum;
        }
    }
}

// ---------- barrier-free wave-per-dst softmax + gather aggregate ----------
// One wave per dst. Lane owns 4 columns (8 B bf16). S=128: 2 edges/iter
// (half-wave each); S=192: 1 edge across lanes 0..47. Per-component weight
// sums make normalization lane-local. No LDS, no __syncthreads.
template <int D, int S, bool RELU>
__global__ void __launch_bounds__(256) agg_k(const float* __restrict__ el,
                                             const float* __restrict__ er,
                                             const bf16* __restrict__ fs,
                                             const int* __restrict__ rowptr,
                                             const int* __restrict__ col,
                                             float* __restrict__ out, int N) {
    constexpr int LPE = S / 4;                  // lanes per edge (32 or 48)
    constexpr int EPW = (LPE <= 32) ? 2 : 1;    // edges in flight per wave
    const int wave = threadIdx.x >> 6, lane = threadIdx.x & 63;
    const int d = blockIdx.x * 4 + wave;
    if (d >= N) return;
    const int sub = lane / LPE;
    const int lg  = lane % LPE;
    const int c0  = 4 * lg;
    const int rs = rowptr[d], re = rowptr[d + 1];

    if (re == rs) {                             // isolated node -> zero row
        if (sub == 0) *(float4*)(out + (size_t)d * S + c0) = make_float4(0, 0, 0, 0);
        return;
    }

    const float4 er4 = *(const float4*)(er + (size_t)d * 4);

    if constexpr (D % 4 == 0) {
        // all 4 components share one head
        const int h0 = c0 / D;
        const float erh = sel4(er4, h0);
        float a0 = 0, a1 = 0, a2 = 0, a3 = 0, sw = 0;
#pragma unroll 2
        for (int i = rs; i < re; i += EPW) {
            int e = i + sub;
            bool v = (sub < EPW) && (e < re);
            int s = col[v ? e : rs];
            float x = el[(size_t)s * 4 + h0] + erh;
            x = x >= 0.f ? x : 0.2f * x;
            float w = v ? __expf(x) : 0.f;
            uint2 u = *(const uint2*)(fs + (size_t)s * S + c0);
            a0 += w * bl(u.x); a1 += w * bh(u.x);
            a2 += w * bl(u.y); a3 += w * bh(u.y);
            sw += w;
        }
        if (EPW == 2) {
            a0 += __shfl_xor(a0, 32); a1 += __shfl_xor(a1, 32);
            a2 += __shfl_xor(a2, 32); a3 += __shfl_xor(a3, 32);
            sw += __shfl_xor(sw, 32);
        }
        if (sub == 0) {
            float4 v4 = make_float4(a0 / sw, a1 / sw, a2 / sw, a3 / sw);
            if (RELU) {
                v4.x = fmaxf(v4.x, 0.f); v4.y = fmaxf(v4.y, 0.f);
                v4.z = fmaxf(v4.z, 0.f); v4.w = fmaxf(v4.w, 0.f);
            }
            *(float4*)(out + (size_t)d * S + c0) = v4;
        }
    } else {
        // D=47: components may straddle a head boundary (<=2 distinct heads)
        const int ha = min(c0 / D, 3);
        const int hb = min((c0 + 3) / D, 3);
        int hk[4];
#pragma unroll
        for (int k = 0; k < 4; ++k) hk[k] = min((c0 + k) / D, 3);
        const float erha = sel4(er4, ha), erhb = sel4(er4, hb);
        float a[4] = {0, 0, 0, 0}, swc[4] = {0, 0, 0, 0};
#pragma unroll 2
        for (int i = rs; i < re; ++i) {
            int s = col[i];
            float4 e4 = *(const float4*)(el + (size_t)s * 4);
            float xa = sel4(e4, ha) + erha;
            xa = xa >= 0.f ? xa : 0.2f * xa;
            float wa = __expf(xa);
            float wb = wa;
            if (hb != ha) {
                float xb = sel4(e4, hb) + erhb;
                xb = xb >= 0.f ? xb : 0.2f * xb;
                wb = __expf(xb);
            }
            uint2 u = *(const uint2*)(fs + (size_t)s * S + c0);
            float f[4] = {bl(u.x), bh(u.x), bl(u.y), bh(u.y)};
#pragma unroll
            for (int k = 0; k < 4; ++k) {
                float w = (hk[k] == ha) ? wa : wb;
                a[k] += w * f[k];
                swc[k] += w;
            }
        }
        if (sub == 0) {
            float4 v4 = make_float4(a[0] / swc[0], a[1] / swc[1],
                                    a[2] / swc[2], a[3] / swc[3]);
            if (RELU) {
                v4.x = fmaxf(v4.x, 0.f); v4.y = fmaxf(v4.y, 0.f);
                v4.z = fmaxf(v4.z, 0.f); v4.w = fmaxf(v4.w, 0.f);
            }
            *(float4*)(out + (size_t)d * S + c0) = v4;
        }
    }
}

// ---------- head-mean + log_softmax (row stride 192) ----------
__global__ void final_k(const float* __restrict__ acc, void* __restrict__ out,
                        const int* __restrict__ flag, int N) {
    int n = blockIdx.x;
    int c = threadIdx.x;
    const bool bf = (*flag != 0);
    const float* p = acc + (size_t)n * 192;
    float val = 0.f, v = -INFINITY;
    if (c < 47) {
        val = 0.25f * (p[c] + p[47 + c] + p[94 + c] + p[141 + c]);
        v = val;
    }
    float m = v;
#pragma unroll
    for (int off = 32; off >= 1; off >>= 1) m = fmaxf(m, __shfl_xor(m, off));
    float ex = (c < 47) ? __expf(val - m) : 0.f;
    float s = ex;
#pragma unroll
    for (int off = 32; off >= 1; off >>= 1) s += __shfl_xor(s, off);
    if (c < 47) {
        float r = val - m - logf(s);
        if (bf) ((bf16*)out)[(size_t)n * 47 + c] = __float2bfloat16(r);
        else    ((float*)out)[(size_t)n * 47 + c] = r;
    }
}

extern "C" void kernel_launch(void* const* d_in, const int* in_sizes, int n_in,
                              void* d_out, int out_size, void* d_ws, size_t ws_size,
                              hipStream_t stream) {
    const void* x   = d_in[0];
    const void* W0  = d_in[1];
    const void* al0 = d_in[2];
    const void* ar0 = d_in[3];
    const void* W1  = d_in[4];
    const void* al1 = d_in[5];
    const void* ar1 = d_in[6];
    const void* W2  = d_in[7];
    const void* al2 = d_in[8];
    const void* ar2 = d_in[9];
    const int* src  = (const int*)d_in[10];
    const int* dst  = (const int*)d_in[11];
    const int E = in_sizes[10];
    const int N = NN;

    bf16* fs    = (bf16*)d_ws;                    // N*192 bf16
    float* hbuf = (float*)(fs + (size_t)N * 192); // N*192 f32
    float* el   = hbuf + (size_t)N * 192;         // N*4
    float* er   = el + (size_t)N * H;             // N*4
    int* rowptr = (int*)(er + (size_t)N * H);     // N+1
    int* cur    = rowptr + (N + 1);               // N
    int* col    = cur + N;                        // E
    int* bsum   = col + E;                        // 256
    int* boff   = bsum + 256;                     // 256
    int* flag   = boff + 256;                     // 1

    const int gN = (N + 255) / 256;               // 196 blocks
    const int gE = (E + 255) / 256;
    const int gG = (N + 63) / 64;                 // 782 gemm blocks
    const int gA = (N + 3) / 4;                   // 12500 agg blocks

    detect_k<<<1, 256, 0, stream>>>(x, flag);

    // CSR build (graph identical for all 3 layers)
    zero_i_k<<<gN, 256, 0, stream>>>(cur, N);
    deg_k<<<gE, 256, 0, stream>>>(dst, cur, E);
    scan1_k<<<gN, 256, 0, stream>>>(cur, rowptr, bsum, N);
    scan2_k<<<1, 256, 0, stream>>>(bsum, boff, gN);
    scan3_k<<<gN, 256, 0, stream>>>(rowptr, boff, N, E);
    zero_i_k<<<gN, 256, 0, stream>>>(cur, N);
    fill_k<<<gE, 256, 0, stream>>>(src, dst, rowptr, cur, col, E);

    // ---------------- Layer 0: Fin=100, M=S=128, D=32 ----------------
    gemm_k<100, 128, 128, 32, true><<<gG, 256, 0, stream>>>(
        x, W0, al0, ar0, fs, el, er, flag, N);
    agg_k<32, 128, true><<<gA, 256, 0, stream>>>(el, er, fs, rowptr, col, hbuf, N);

    // ---------------- Layer 1: Fin=128, M=S=128, D=32 ----------------
    gemm_k<128, 128, 128, 32, false><<<gG, 256, 0, stream>>>(
        hbuf, W1, al1, ar1, fs, el, er, flag, N);
    agg_k<32, 128, true><<<gA, 256, 0, stream>>>(el, er, fs, rowptr, col, hbuf, N);

    // ---------------- Layer 2: Fin=128, M=188, S=192, D=47 ----------------
    gemm_k<128, 188, 192, 47, false><<<gG, 256, 0, stream>>>(
        hbuf, W2, al2, ar2, fs, el, er, flag, N);
    agg_k<47, 192, false><<<gA, 256, 0, stream>>>(el, er, fs, rowptr, col, hbuf, N);

    final_k<<<N, 64, 0, stream>>>(hbuf, d_out, flag, N);
}

// Round 8
// 825.933 us; speedup vs baseline: 1.0063x; 1.0063x over previous
//
#include <hip/hip_runtime.h>
#include <hip/hip_bf16.h>

// GAT 3-layer forward. N=50000, E=1.6M, H=4, D=32, C=47.
// Round 8: agg back to block-gather (round-6 shape: 16B/lane, weights once
// per edge) + double-buffered weight staging (1 barrier/chunk, weight gather
// overlaps fs gather) + 16 edges in flight for layer 2 (TPB=384).
// el/er stay fused in the MFMA-gemm epilogue.
//
// ws: fs_bf[N*192 bf16] hbuf[N*192 f32] el[N*4] er[N*4] rowptr[N+1] cur[N]
//     col[E] bsum/boff[512] flag  => ~66 MB.

using bf16 = __hip_bfloat16;
typedef __attribute__((ext_vector_type(8))) short short8;
typedef __attribute__((ext_vector_type(4))) float floatx4;

static constexpr int NN = 50000;
static constexpr int H  = 4;

__device__ __forceinline__ float b2f(bf16 x) { return __bfloat162float(x); }
__device__ __forceinline__ float ldx(const void* p, size_t i, bool bf) {
    return bf ? __bfloat162float(((const bf16*)p)[i]) : ((const float*)p)[i];
}
__device__ __forceinline__ unsigned short f2b_bits(float v) {
    bf16 h = __float2bfloat16(v);
    return *reinterpret_cast<unsigned short*>(&h);
}
__device__ __forceinline__ unsigned short w_bits(const void* p, size_t i, bool bf) {
    if (bf) return ((const unsigned short*)p)[i];
    return f2b_bits(((const float*)p)[i]);
}
__device__ __forceinline__ float bl(unsigned u) { return __uint_as_float(u << 16); }
__device__ __forceinline__ float bh(unsigned u) { return __uint_as_float(u & 0xFFFF0000u); }

// ---------- dtype detection (bf16 vs fp32) ----------
__global__ void detect_k(const void* __restrict__ x, int* __restrict__ flag) {
    __shared__ int cnt;
    if (threadIdx.x == 0) cnt = 0;
    __syncthreads();
    const unsigned short* u = (const unsigned short*)x;
    unsigned short b = u[threadIdx.x * 2];
    int e = (b >> 7) & 0xFF;
    if (e >= 0x70 && e <= 0x8F) atomicAdd(&cnt, 1);
    __syncthreads();
    if (threadIdx.x == 0) *flag = (cnt > 128) ? 1 : 0;
}

__global__ void zero_i_k(int* __restrict__ p, int n) {
    int i = blockIdx.x * 256 + threadIdx.x;
    if (i < n) p[i] = 0;
}

// ---------- CSR build (by dst) ----------
__global__ void deg_k(const int* __restrict__ dst, int* __restrict__ deg, int E) {
    int e = blockIdx.x * 256 + threadIdx.x;
    if (e < E) atomicAdd(&deg[dst[e]], 1);
}

__global__ void scan1_k(const int* __restrict__ deg, int* __restrict__ rowptr,
                        int* __restrict__ bsum, int N) {
    __shared__ int buf[256];
    int tid = threadIdx.x, i = blockIdx.x * 256 + tid;
    int v = (i < N) ? deg[i] : 0;
    buf[tid] = v;
    __syncthreads();
    for (int off = 1; off < 256; off <<= 1) {
        int t = (tid >= off) ? buf[tid - off] : 0;
        __syncthreads();
        buf[tid] += t;
        __syncthreads();
    }
    if (i < N) rowptr[i] = buf[tid] - v;
    if (tid == 255) bsum[blockIdx.x] = buf[255];
}

__global__ void scan2_k(const int* __restrict__ bsum, int* __restrict__ boff, int nb) {
    __shared__ int buf[256];
    int tid = threadIdx.x;
    int v = (tid < nb) ? bsum[tid] : 0;
    buf[tid] = v;
    __syncthreads();
    for (int off = 1; off < 256; off <<= 1) {
        int t = (tid >= off) ? buf[tid - off] : 0;
        __syncthreads();
        buf[tid] += t;
        __syncthreads();
    }
    if (tid < nb) boff[tid] = buf[tid] - v;
}

__global__ void scan3_k(int* __restrict__ rowptr, const int* __restrict__ boff,
                        int N, int E) {
    int i = blockIdx.x * 256 + threadIdx.x;
    if (i < N) rowptr[i] += boff[blockIdx.x];
    if (i == 0) rowptr[N] = E;
}

__global__ void fill_k(const int* __restrict__ src, const int* __restrict__ dst,
                       const int* __restrict__ rowptr, int* __restrict__ cur,
                       int* __restrict__ col, int E) {
    int e = blockIdx.x * 256 + threadIdx.x;
    if (e >= E) return;
    int d = dst[e];
    int p = atomicAdd(&cur[d], 1);
    col[rowptr[d] + p] = src[e];
}

// ---------- MFMA GEMM + fused el/er epilogue ----------
// Block = 4 waves = 64 nodes. W^T in LDS bf16 (stride 136 shorts). K padded
// to 128. mfma_f32_16x16x32_bf16; D-layout: col=lane&15, row=(lane>>4)*4+reg.
// Epilogue computes el/er from fp32 accumulators via LDS reduce (reuses wlds).
template <int K, int M, int S, int HD, bool IN_EXT>
__global__ void __launch_bounds__(256) gemm_k(const void* __restrict__ in,
                                              const void* __restrict__ W,
                                              const void* __restrict__ al,
                                              const void* __restrict__ ar,
                                              bf16* __restrict__ fs,
                                              float* __restrict__ el,
                                              float* __restrict__ er,
                                              const int* __restrict__ flag, int N) {
    constexpr int KP  = 128;
    constexpr int CT  = S / 16;
    constexpr int WST = 136;
    __shared__ short wlds[S * WST];
    const bool bf = (*flag != 0);
    const int tid = threadIdx.x;

    // ---- stage W^T (c-major) into LDS, zero-pad k>=K and c>=M ----
    for (int idx = tid; idx < (KP / 2) * M; idx += 256) {
        int k2 = idx / M, c = idx % M;
        int k0 = 2 * k2;
        unsigned short u0 = (k0 < K)     ? w_bits(W, (size_t)k0 * M + c, bf)       : 0;
        unsigned short u1 = (k0 + 1 < K) ? w_bits(W, (size_t)(k0 + 1) * M + c, bf) : 0;
        *(unsigned*)&wlds[c * WST + 2 * k2] = (unsigned)u0 | ((unsigned)u1 << 16);
    }
    if (S > M) {
        for (int idx = tid; idx < (S - M) * (KP / 2); idx += 256) {
            int c = M + idx / (KP / 2);
            int k2 = idx % (KP / 2);
            *(unsigned*)&wlds[c * WST + 2 * k2] = 0u;
        }
    }
    __syncthreads();

    const int wave = tid >> 6, lane = tid & 63;
    const int q = lane >> 4, l16 = lane & 15;
    const int tile_base = blockIdx.x * 64 + wave * 16;
    const int node_a = tile_base + l16;

    floatx4 acc[CT] = {};

#pragma unroll
    for (int chunk = 0; chunk < 4; ++chunk) {
        const int kb = chunk * 32 + q * 8;
        short8 a;
        if (IN_EXT) {
#pragma unroll
            for (int j = 0; j < 8; ++j) {
                int k = kb + j;
                float v = (node_a < N && k < K) ? ldx(in, (size_t)node_a * K + k, bf) : 0.f;
                a[j] = (short)f2b_bits(v);
            }
        } else {
            const float* f = (const float*)in + (size_t)node_a * K + kb;
            float4 f0 = make_float4(0, 0, 0, 0), f1 = f0;
            if (node_a < N) { f0 = *(const float4*)f; f1 = *(const float4*)(f + 4); }
            a[0] = (short)f2b_bits(f0.x); a[1] = (short)f2b_bits(f0.y);
            a[2] = (short)f2b_bits(f0.z); a[3] = (short)f2b_bits(f0.w);
            a[4] = (short)f2b_bits(f1.x); a[5] = (short)f2b_bits(f1.y);
            a[6] = (short)f2b_bits(f1.z); a[7] = (short)f2b_bits(f1.w);
        }
#pragma unroll
        for (int ct = 0; ct < CT; ++ct) {
            const int c = ct * 16 + l16;
            short8 b = *(const short8*)&wlds[c * WST + kb];
            acc[ct] = __builtin_amdgcn_mfma_f32_16x16x32_bf16(a, b, acc[ct], 0, 0, 0);
        }
    }

    // ---- store fs ----
#pragma unroll
    for (int ct = 0; ct < CT; ++ct) {
        const int c = ct * 16 + l16;
#pragma unroll
        for (int r = 0; r < 4; ++r) {
            int node = tile_base + q * 4 + r;
            if (node < N) fs[(size_t)node * S + c] = __float2bfloat16(acc[ct][r]);
        }
    }

    // ---- fused el/er: el[n,h] = sum_c fs[n,c]*al[c] (fp32 acc) ----
    __syncthreads();                    // all wlds reads done; reuse as red buf
    float* red = (float*)wlds;          // 512 slots x 16 floats = 32 KB
    float elp[4][4] = {}, erp[4][4] = {};
#pragma unroll
    for (int ct = 0; ct < CT; ++ct) {
        const int c = ct * 16 + l16;
        float alc = (c < M) ? ldx(al, c, bf) : 0.f;
        float arc = (c < M) ? ldx(ar, c, bf) : 0.f;
        const int h = (c < M) ? (c / HD) : 3;
#pragma unroll
        for (int r = 0; r < 4; ++r) {
            float v = acc[ct][r];
#pragma unroll
            for (int h2 = 0; h2 < 4; ++h2) {
                elp[r][h2] += (h == h2) ? v * alc : 0.f;
                erp[r][h2] += (h == h2) ? v * arc : 0.f;
            }
        }
    }
#pragma unroll
    for (int r = 0; r < 4; ++r)
#pragma unroll
        for (int h2 = 0; h2 < 4; ++h2) {
            int slot = (wave * 128) + (q * 32) + (r * 8) + (h2 * 2);
            red[slot * 16 + l16] = elp[r][h2];
            red[(slot + 1) * 16 + l16] = erp[r][h2];
        }
    __syncthreads();
#pragma unroll
    for (int pass = 0; pass < 2; ++pass) {
        int slot = tid + pass * 256;
        float sum = 0.f;
#pragma unroll
        for (int j = 0; j < 16; ++j) sum += red[slot * 16 + j];
        int which = slot & 1;
        int h2 = (slot >> 1) & 3;
        int r  = (slot >> 3) & 3;
        int qq = (slot >> 5) & 3;
        int wv = slot >> 7;
        int node = blockIdx.x * 64 + wv * 16 + qq * 4 + r;
        if (node < N) {
            if (which == 0) el[(size_t)node * 4 + h2] = sum;
            else            er[(size_t)node * 4 + h2] = sum;
        }
    }
}

// ---------- block softmax + gather aggregate, double-buffered weights ----------
// One block per dst. LPG=S/8 lanes per edge, each loads uint4 (16 B = 8 bf16
// cols). NG=TPB/LPG edges in flight. Weights for chunk t+1 staged while
// gathering chunk t -> ONE barrier per chunk. No max pass (scores O(6)).
template <int D, int S, int LPG, int TPB, bool RELU>
__global__ void __launch_bounds__(TPB) agg_k(const float* __restrict__ el,
                                             const float* __restrict__ er,
                                             const bf16* __restrict__ fs,
                                             const int* __restrict__ rowptr,
                                             const int* __restrict__ col,
                                             float* __restrict__ out) {
    constexpr int NG = TPB / LPG;       // edges in flight (16)
    const int d = blockIdx.x;
    const int tid = threadIdx.x;
    const int rs = rowptr[d], re = rowptr[d + 1];

    __shared__ float wlds[2][NG][4];
    __shared__ int scol[2][NG];
    __shared__ float part[NG][S];
    __shared__ float sh_s[4];

    if (re == rs) {                     // isolated node -> zero row
        if (tid < S / 4) *(float4*)(out + (size_t)d * S + tid * 4) = make_float4(0, 0, 0, 0);
        return;
    }

    float4 er4 = *(const float4*)(er + (size_t)d * 4);
    float er_d[4] = {er4.x, er4.y, er4.z, er4.w};

    const int g  = tid / LPG;
    const int lg = tid % LPG;
    const int c0 = lg * 8;
    int hh[8];
#pragma unroll
    for (int k = 0; k < 8; ++k) hh[k] = min((c0 + k) / D, 3);

    float acc[8] = {0, 0, 0, 0, 0, 0, 0, 0};
    float swpart = 0.f;

    // stage chunk 0 into buf 0
    {
        int ne0 = min(NG, re - rs);
        if (tid < ne0 * 4) {
            int j = tid >> 2, h = tid & 3;
            int s = col[rs + j];
            if (h == 0) scol[0][j] = s;
            float x = el[(size_t)s * 4 + h] + er_d[h];
            x = x >= 0.f ? x : 0.2f * x;
            float w = __expf(x);
            wlds[0][j][h] = w;
            swpart += w;
        }
    }
    __syncthreads();

    int b = 0;
    for (int cs = rs; cs < re; cs += NG, b ^= 1) {
        int ne = min(NG, re - cs);
        int ns = cs + NG;
        int ne2 = (ns < re) ? min(NG, re - ns) : 0;
        // stage next chunk into the other buffer (overlaps fs gather below)
        if (tid < ne2 * 4) {
            int j = tid >> 2, h = tid & 3;
            int s = col[ns + j];
            if (h == 0) scol[b ^ 1][j] = s;
            float x = el[(size_t)s * 4 + h] + er_d[h];
            x = x >= 0.f ? x : 0.2f * x;
            float w = __expf(x);
            wlds[b ^ 1][j][h] = w;
            swpart += w;
        }
        // gather current chunk
        if (g < ne) {
            int s = scol[b][g];
            uint4 u = *(const uint4*)(fs + (size_t)s * S + c0);
            float f[8];
            f[0] = bl(u.x); f[1] = bh(u.x);
            f[2] = bl(u.y); f[3] = bh(u.y);
            f[4] = bl(u.z); f[5] = bh(u.z);
            f[6] = bl(u.w); f[7] = bh(u.w);
            float wg[4] = {wlds[b][g][0], wlds[b][g][1], wlds[b][g][2], wlds[b][g][3]};
#pragma unroll
            for (int k = 0; k < 8; ++k) acc[k] += wg[hh[k]] * f[k];
        }
        __syncthreads();
    }
#pragma unroll
    for (int k = 0; k < 8; ++k) part[g][c0 + k] = acc[k];

    // per-head weight sums: staging threads are tid < NG*4 <= 64 (wave 0)
    float sw = swpart;
#pragma unroll
    for (int off = 4; off < 64; off <<= 1) sw += __shfl_xor(sw, off);
    if (tid < 4) sh_s[tid] = sw;
    __syncthreads();

    if (tid < S / 4) {
        int c = tid * 4;
        float4 v = make_float4(0, 0, 0, 0);
#pragma unroll
        for (int gg = 0; gg < NG; ++gg) {
            v.x += part[gg][c + 0]; v.y += part[gg][c + 1];
            v.z += part[gg][c + 2]; v.w += part[gg][c + 3];
        }
        v.x /= sh_s[min((c + 0) / D, 3)];
        v.y /= sh_s[min((c + 1) / D, 3)];
        v.z /= sh_s[min((c + 2) / D, 3)];
        v.w /= sh_s[min((c + 3) / D, 3)];
        if (RELU) {
            v.x = fmaxf(v.x, 0.f); v.y = fmaxf(v.y, 0.f);
            v.z = fmaxf(v.z, 0.f); v.w = fmaxf(v.w, 0.f);
        }
        *(float4*)(out + (size_t)d * S + c) = v;
    }
}

// ---------- head-mean + log_softmax (row stride 192) ----------
__global__ void final_k(const float* __restrict__ acc, void* __restrict__ out,
                        const int* __restrict__ flag, int N) {
    int n = blockIdx.x;
    int c = threadIdx.x;
    const bool bf = (*flag != 0);
    const float* p = acc + (size_t)n * 192;
    float val = 0.f, v = -INFINITY;
    if (c < 47) {
        val = 0.25f * (p[c] + p[47 + c] + p[94 + c] + p[141 + c]);
        v = val;
    }
    float m = v;
#pragma unroll
    for (int off = 32; off >= 1; off >>= 1) m = fmaxf(m, __shfl_xor(m, off));
    float ex = (c < 47) ? __expf(val - m) : 0.f;
    float s = ex;
#pragma unroll
    for (int off = 32; off >= 1; off >>= 1) s += __shfl_xor(s, off);
    if (c < 47) {
        float r = val - m - logf(s);
        if (bf) ((bf16*)out)[(size_t)n * 47 + c] = __float2bfloat16(r);
        else    ((float*)out)[(size_t)n * 47 + c] = r;
    }
}

extern "C" void kernel_launch(void* const* d_in, const int* in_sizes, int n_in,
                              void* d_out, int out_size, void* d_ws, size_t ws_size,
                              hipStream_t stream) {
    const void* x   = d_in[0];
    const void* W0  = d_in[1];
    const void* al0 = d_in[2];
    const void* ar0 = d_in[3];
    const void* W1  = d_in[4];
    const void* al1 = d_in[5];
    const void* ar1 = d_in[6];
    const void* W2  = d_in[7];
    const void* al2 = d_in[8];
    const void* ar2 = d_in[9];
    const int* src  = (const int*)d_in[10];
    const int* dst  = (const int*)d_in[11];
    const int E = in_sizes[10];
    const int N = NN;

    bf16* fs    = (bf16*)d_ws;                    // N*192 bf16
    float* hbuf = (float*)(fs + (size_t)N * 192); // N*192 f32
    float* el   = hbuf + (size_t)N * 192;         // N*4
    float* er   = el + (size_t)N * H;             // N*4
    int* rowptr = (int*)(er + (size_t)N * H);     // N+1
    int* cur    = rowptr + (N + 1);               // N
    int* col    = cur + N;                        // E
    int* bsum   = col + E;                        // 256
    int* boff   = bsum + 256;                     // 256
    int* flag   = boff + 256;                     // 1

    const int gN = (N + 255) / 256;               // 196 blocks
    const int gE = (E + 255) / 256;
    const int gG = (N + 63) / 64;                 // 782 gemm blocks

    detect_k<<<1, 256, 0, stream>>>(x, flag);

    // CSR build (graph identical for all 3 layers)
    zero_i_k<<<gN, 256, 0, stream>>>(cur, N);
    deg_k<<<gE, 256, 0, stream>>>(dst, cur, E);
    scan1_k<<<gN, 256, 0, stream>>>(cur, rowptr, bsum, N);
    scan2_k<<<1, 256, 0, stream>>>(bsum, boff, gN);
    scan3_k<<<gN, 256, 0, stream>>>(rowptr, boff, N, E);
    zero_i_k<<<gN, 256, 0, stream>>>(cur, N);
    fill_k<<<gE, 256, 0, stream>>>(src, dst, rowptr, cur, col, E);

    // ---------------- Layer 0: Fin=100, M=S=128, D=32 ----------------
    gemm_k<100, 128, 128, 32, true><<<gG, 256, 0, stream>>>(
        x, W0, al0, ar0, fs, el, er, flag, N);
    agg_k<32, 128, 16, 256, true><<<N, 256, 0, stream>>>(el, er, fs, rowptr, col, hbuf);

    // ---------------- Layer 1: Fin=128, M=S=128, D=32 ----------------
    gemm_k<128, 128, 128, 32, false><<<gG, 256, 0, stream>>>(
        hbuf, W1, al1, ar1, fs, el, er, flag, N);
    agg_k<32, 128, 16, 256, true><<<N, 256, 0, stream>>>(el, er, fs, rowptr, col, hbuf);

    // ---------------- Layer 2: Fin=128, M=188, S=192, D=47 ----------------
    gemm_k<128, 188, 192, 47, false><<<gG, 256, 0, stream>>>(
        hbuf, W2, al2, ar2, fs, el, er, flag, N);
    agg_k<47, 192, 24, 384, false><<<N, 384, 0, stream>>>(el, er, fs, rowptr, col, hbuf);

    final_k<<<N, 64, 0, stream>>>(hbuf, d_out, flag, N);
}

// Round 9
// 643.808 us; speedup vs baseline: 1.2910x; 1.2829x over previous
//
#include <hip/hip_runtime.h>
#include <hip/hip_bf16.h>

// GAT 3-layer forward. N=50000, E=1.6M, H=4, D=32, C=47.
// Round 9: agg with whole-row weight staging (CH=TPB/4 edges, 2 barriers per
// block) + barrier-free unrolled gather loop (4 fs-loads in flight per lane).
// Layers 0/1 intermediate stored bf16 (direct short8 GEMM A-load).
//
// ws: fs_bf[N*192 bf16] hb16[N*128 bf16] hbuf[N*192 f32] el/er[N*4]
//     rowptr cur col bsum boff flag  => ~79 MB.

using bf16 = __hip_bfloat16;
typedef __attribute__((ext_vector_type(8))) short short8;
typedef __attribute__((ext_vector_type(4))) float floatx4;

static constexpr int NN = 50000;
static constexpr int H  = 4;

__device__ __forceinline__ float b2f(bf16 x) { return __bfloat162float(x); }
__device__ __forceinline__ float ldx(const void* p, size_t i, bool bf) {
    return bf ? __bfloat162float(((const bf16*)p)[i]) : ((const float*)p)[i];
}
__device__ __forceinline__ unsigned short f2b_bits(float v) {
    bf16 h = __float2bfloat16(v);
    return *reinterpret_cast<unsigned short*>(&h);
}
__device__ __forceinline__ unsigned short w_bits(const void* p, size_t i, bool bf) {
    if (bf) return ((const unsigned short*)p)[i];
    return f2b_bits(((const float*)p)[i]);
}
__device__ __forceinline__ float bl(unsigned u) { return __uint_as_float(u << 16); }
__device__ __forceinline__ float bh(unsigned u) { return __uint_as_float(u & 0xFFFF0000u); }

// ---------- dtype detection (bf16 vs fp32) ----------
__global__ void detect_k(const void* __restrict__ x, int* __restrict__ flag) {
    __shared__ int cnt;
    if (threadIdx.x == 0) cnt = 0;
    __syncthreads();
    const unsigned short* u = (const unsigned short*)x;
    unsigned short b = u[threadIdx.x * 2];
    int e = (b >> 7) & 0xFF;
    if (e >= 0x70 && e <= 0x8F) atomicAdd(&cnt, 1);
    __syncthreads();
    if (threadIdx.x == 0) *flag = (cnt > 128) ? 1 : 0;
}

__global__ void zero_i_k(int* __restrict__ p, int n) {
    int i = blockIdx.x * 256 + threadIdx.x;
    if (i < n) p[i] = 0;
}

// ---------- CSR build (by dst) ----------
__global__ void deg_k(const int* __restrict__ dst, int* __restrict__ deg, int E) {
    int e = blockIdx.x * 256 + threadIdx.x;
    if (e < E) atomicAdd(&deg[dst[e]], 1);
}

__global__ void scan1_k(const int* __restrict__ deg, int* __restrict__ rowptr,
                        int* __restrict__ bsum, int N) {
    __shared__ int buf[256];
    int tid = threadIdx.x, i = blockIdx.x * 256 + tid;
    int v = (i < N) ? deg[i] : 0;
    buf[tid] = v;
    __syncthreads();
    for (int off = 1; off < 256; off <<= 1) {
        int t = (tid >= off) ? buf[tid - off] : 0;
        __syncthreads();
        buf[tid] += t;
        __syncthreads();
    }
    if (i < N) rowptr[i] = buf[tid] - v;
    if (tid == 255) bsum[blockIdx.x] = buf[255];
}

__global__ void scan2_k(const int* __restrict__ bsum, int* __restrict__ boff, int nb) {
    __shared__ int buf[256];
    int tid = threadIdx.x;
    int v = (tid < nb) ? bsum[tid] : 0;
    buf[tid] = v;
    __syncthreads();
    for (int off = 1; off < 256; off <<= 1) {
        int t = (tid >= off) ? buf[tid - off] : 0;
        __syncthreads();
        buf[tid] += t;
        __syncthreads();
    }
    if (tid < nb) boff[tid] = buf[tid] - v;
}

__global__ void scan3_k(int* __restrict__ rowptr, const int* __restrict__ boff,
                        int N, int E) {
    int i = blockIdx.x * 256 + threadIdx.x;
    if (i < N) rowptr[i] += boff[blockIdx.x];
    if (i == 0) rowptr[N] = E;
}

__global__ void fill_k(const int* __restrict__ src, const int* __restrict__ dst,
                       const int* __restrict__ rowptr, int* __restrict__ cur,
                       int* __restrict__ col, int E) {
    int e = blockIdx.x * 256 + threadIdx.x;
    if (e >= E) return;
    int d = dst[e];
    int p = atomicAdd(&cur[d], 1);
    col[rowptr[d] + p] = src[e];
}

// ---------- MFMA GEMM + fused el/er epilogue ----------
// Block = 4 waves = 64 nodes. W^T in LDS bf16 (stride 136 shorts). K padded
// to 128. mfma_f32_16x16x32_bf16; D-layout: col=lane&15, row=(lane>>4)*4+reg.
// IN_MODE: 0 = external (runtime dtype, guarded scalar), 1 = internal bf16
// (direct short8 load, K must be multiple of 8).
template <int K, int M, int S, int HD, int IN_MODE>
__global__ void __launch_bounds__(256) gemm_k(const void* __restrict__ in,
                                              const void* __restrict__ W,
                                              const void* __restrict__ al,
                                              const void* __restrict__ ar,
                                              bf16* __restrict__ fs,
                                              float* __restrict__ el,
                                              float* __restrict__ er,
                                              const int* __restrict__ flag, int N) {
    constexpr int KP  = 128;
    constexpr int CT  = S / 16;
    constexpr int WST = 136;
    __shared__ short wlds[S * WST];
    const bool bf = (*flag != 0);
    const int tid = threadIdx.x;

    // ---- stage W^T (c-major) into LDS, zero-pad k>=K and c>=M ----
    for (int idx = tid; idx < (KP / 2) * M; idx += 256) {
        int k2 = idx / M, c = idx % M;
        int k0 = 2 * k2;
        unsigned short u0 = (k0 < K)     ? w_bits(W, (size_t)k0 * M + c, bf)       : 0;
        unsigned short u1 = (k0 + 1 < K) ? w_bits(W, (size_t)(k0 + 1) * M + c, bf) : 0;
        *(unsigned*)&wlds[c * WST + 2 * k2] = (unsigned)u0 | ((unsigned)u1 << 16);
    }
    if (S > M) {
        for (int idx = tid; idx < (S - M) * (KP / 2); idx += 256) {
            int c = M + idx / (KP / 2);
            int k2 = idx % (KP / 2);
            *(unsigned*)&wlds[c * WST + 2 * k2] = 0u;
        }
    }
    __syncthreads();

    const int wave = tid >> 6, lane = tid & 63;
    const int q = lane >> 4, l16 = lane & 15;
    const int tile_base = blockIdx.x * 64 + wave * 16;
    const int node_a = tile_base + l16;

    floatx4 acc[CT] = {};

#pragma unroll
    for (int chunk = 0; chunk < 4; ++chunk) {
        const int kb = chunk * 32 + q * 8;
        short8 a = {};
        if (IN_MODE == 0) {
#pragma unroll
            for (int j = 0; j < 8; ++j) {
                int k = kb + j;
                float v = (node_a < N && k < K) ? ldx(in, (size_t)node_a * K + k, bf) : 0.f;
                a[j] = (short)f2b_bits(v);
            }
        } else {
            if (node_a < N)
                a = *(const short8*)((const bf16*)in + (size_t)node_a * K + kb);
        }
#pragma unroll
        for (int ct = 0; ct < CT; ++ct) {
            const int c = ct * 16 + l16;
            short8 b = *(const short8*)&wlds[c * WST + kb];
            acc[ct] = __builtin_amdgcn_mfma_f32_16x16x32_bf16(a, b, acc[ct], 0, 0, 0);
        }
    }

    // ---- store fs ----
#pragma unroll
    for (int ct = 0; ct < CT; ++ct) {
        const int c = ct * 16 + l16;
#pragma unroll
        for (int r = 0; r < 4; ++r) {
            int node = tile_base + q * 4 + r;
            if (node < N) fs[(size_t)node * S + c] = __float2bfloat16(acc[ct][r]);
        }
    }

    // ---- fused el/er from fp32 accumulators (LDS reduce, reuse wlds) ----
    __syncthreads();
    float* red = (float*)wlds;          // 512 slots x 16 floats = 32 KB
    float elp[4][4] = {}, erp[4][4] = {};
#pragma unroll
    for (int ct = 0; ct < CT; ++ct) {
        const int c = ct * 16 + l16;
        float alc = (c < M) ? ldx(al, c, bf) : 0.f;
        float arc = (c < M) ? ldx(ar, c, bf) : 0.f;
        const int h = (c < M) ? (c / HD) : 3;
#pragma unroll
        for (int r = 0; r < 4; ++r) {
            float v = acc[ct][r];
#pragma unroll
            for (int h2 = 0; h2 < 4; ++h2) {
                elp[r][h2] += (h == h2) ? v * alc : 0.f;
                erp[r][h2] += (h == h2) ? v * arc : 0.f;
            }
        }
    }
#pragma unroll
    for (int r = 0; r < 4; ++r)
#pragma unroll
        for (int h2 = 0; h2 < 4; ++h2) {
            int slot = (wave * 128) + (q * 32) + (r * 8) + (h2 * 2);
            red[slot * 16 + l16] = elp[r][h2];
            red[(slot + 1) * 16 + l16] = erp[r][h2];
        }
    __syncthreads();
#pragma unroll
    for (int pass = 0; pass < 2; ++pass) {
        int slot = tid + pass * 256;
        float sum = 0.f;
#pragma unroll
        for (int j = 0; j < 16; ++j) sum += red[slot * 16 + j];
        int which = slot & 1;
        int h2 = (slot >> 1) & 3;
        int r  = (slot >> 3) & 3;
        int qq = (slot >> 5) & 3;
        int wv = slot >> 7;
        int node = blockIdx.x * 64 + wv * 16 + qq * 4 + r;
        if (node < N) {
            if (which == 0) el[(size_t)node * 4 + h2] = sum;
            else            er[(size_t)node * 4 + h2] = sum;
        }
    }
}

// ---------- agg: whole-row weight staging + barrier-free unrolled gather ----
// One block per dst. CH=TPB/4 edges staged per round (col + 4 head-weights,
// all TPB threads). Then lanes gather: LPG lanes per edge, 16 B loads, each
// lane strides its edges unrolled 4 deep -> 4 loads in flight. 2 barriers
// per round; one round covers deg <= CH (mean deg 32).
template <int D, int S, int LPG, int TPB, bool RELU, bool OUT_BF>
__global__ void __launch_bounds__(TPB) agg_k(const float* __restrict__ el,
                                             const float* __restrict__ er,
                                             const bf16* __restrict__ fs,
                                             const int* __restrict__ rowptr,
                                             const int* __restrict__ col,
                                             void* __restrict__ out) {
    constexpr int NG = TPB / LPG;       // edge stride in gather loop
    constexpr int CH = TPB / 4;         // edges staged per round
    constexpr int NW = TPB / 64;
    const int d = blockIdx.x;
    const int tid = threadIdx.x;
    const int rs = rowptr[d], re = rowptr[d + 1];

    __shared__ float wrow[CH][4];
    __shared__ int scol_s[CH];
    __shared__ float part[NG][S];
    __shared__ float red2[NW][4];
    __shared__ float sh_s[4];

    if (re == rs) {                     // isolated node -> zero row
        if (tid < S / 4) {
            if (OUT_BF) *(uint2*)((bf16*)out + (size_t)d * S + tid * 4) = make_uint2(0, 0);
            else        *(float4*)((float*)out + (size_t)d * S + tid * 4) = make_float4(0, 0, 0, 0);
        }
        return;
    }

    float4 er4 = *(const float4*)(er + (size_t)d * 4);
    float er_d[4] = {er4.x, er4.y, er4.z, er4.w};

    const int g  = tid / LPG;
    const int lg = tid % LPG;
    const int c0 = lg * 8;
    const int ha = (c0) / D > 3 ? 3 : (c0) / D;
    const int hb = (c0 + 7) / D > 3 ? 3 : (c0 + 7) / D;
    bool kb_mask[8];
#pragma unroll
    for (int k = 0; k < 8; ++k) kb_mask[k] = (((c0 + k) / D > 3 ? 3 : (c0 + k) / D) != ha);

    float acc[8] = {0, 0, 0, 0, 0, 0, 0, 0};
    float swpart = 0.f;                 // partial weight sum for head tid&3

    for (int cs = rs; cs < re; cs += CH) {
        int ne = min(CH, re - cs);
        // ---- stage: col + per-head exp weights (all threads) ----
        if (tid < ne * 4) {
            int j = tid >> 2, h = tid & 3;
            int s = col[cs + j];
            if (h == 0) scol_s[j] = s;
            float x = el[(size_t)s * 4 + h] + er_d[h];
            x = x >= 0.f ? x : 0.2f * x;
            float w = __expf(x);
            wrow[j][h] = w;
            swpart += w;
        }
        __syncthreads();
        // ---- gather: barrier-free, unrolled (independent iterations) ----
#pragma unroll 4
        for (int e = g; e < ne; e += NG) {
            int s = scol_s[e];
            uint4 u = *(const uint4*)(fs + (size_t)s * S + c0);
            float wa = wrow[e][ha];
            float wb = (hb == ha) ? wa : wrow[e][hb];
            float f[8];
            f[0] = bl(u.x); f[1] = bh(u.x);
            f[2] = bl(u.y); f[3] = bh(u.y);
            f[4] = bl(u.z); f[5] = bh(u.z);
            f[6] = bl(u.w); f[7] = bh(u.w);
#pragma unroll
            for (int k = 0; k < 8; ++k) acc[k] += (kb_mask[k] ? wb : wa) * f[k];
        }
        __syncthreads();
    }

    // ---- per-head weight-sum reduce (h = tid&3 fixed per thread) ----
    float sw = swpart;
#pragma unroll
    for (int off = 4; off < 64; off <<= 1) sw += __shfl_xor(sw, off);
    const int wave = tid >> 6, lane = tid & 63;
    if (lane < 4) red2[wave][lane] = sw;
    // ---- cross-group partials ----
#pragma unroll
    for (int k = 0; k < 8; ++k) part[g][c0 + k] = acc[k];
    __syncthreads();
    if (tid < 4) {
        float s = 0.f;
#pragma unroll
        for (int w = 0; w < NW; ++w) s += red2[w][tid];
        sh_s[tid] = s;
    }
    __syncthreads();

    if (tid < S / 4) {
        int c = tid * 4;
        float4 v = make_float4(0, 0, 0, 0);
#pragma unroll
        for (int gg = 0; gg < NG; ++gg) {
            v.x += part[gg][c + 0]; v.y += part[gg][c + 1];
            v.z += part[gg][c + 2]; v.w += part[gg][c + 3];
        }
        v.x /= sh_s[min((c + 0) / D, 3)];
        v.y /= sh_s[min((c + 1) / D, 3)];
        v.z /= sh_s[min((c + 2) / D, 3)];
        v.w /= sh_s[min((c + 3) / D, 3)];
        if (RELU) {
            v.x = fmaxf(v.x, 0.f); v.y = fmaxf(v.y, 0.f);
            v.z = fmaxf(v.z, 0.f); v.w = fmaxf(v.w, 0.f);
        }
        if (OUT_BF) {
            unsigned p0 = (unsigned)f2b_bits(v.x) | ((unsigned)f2b_bits(v.y) << 16);
            unsigned p1 = (unsigned)f2b_bits(v.z) | ((unsigned)f2b_bits(v.w) << 16);
            *(uint2*)((bf16*)out + (size_t)d * S + c) = make_uint2(p0, p1);
        } else {
            *(float4*)((float*)out + (size_t)d * S + c) = v;
        }
    }
}

// ---------- head-mean + log_softmax (fp32 in, row stride 192) ----------
__global__ void final_k(const float* __restrict__ acc, void* __restrict__ out,
                        const int* __restrict__ flag, int N) {
    int n = blockIdx.x;
    int c = threadIdx.x;
    const bool bf = (*flag != 0);
    const float* p = acc + (size_t)n * 192;
    float val = 0.f, v = -INFINITY;
    if (c < 47) {
        val = 0.25f * (p[c] + p[47 + c] + p[94 + c] + p[141 + c]);
        v = val;
    }
    float m = v;
#pragma unroll
    for (int off = 32; off >= 1; off >>= 1) m = fmaxf(m, __shfl_xor(m, off));
    float ex = (c < 47) ? __expf(val - m) : 0.f;
    float s = ex;
#pragma unroll
    for (int off = 32; off >= 1; off >>= 1) s += __shfl_xor(s, off);
    if (c < 47) {
        float r = val - m - logf(s);
        if (bf) ((bf16*)out)[(size_t)n * 47 + c] = __float2bfloat16(r);
        else    ((float*)out)[(size_t)n * 47 + c] = r;
    }
}

extern "C" void kernel_launch(void* const* d_in, const int* in_sizes, int n_in,
                              void* d_out, int out_size, void* d_ws, size_t ws_size,
                              hipStream_t stream) {
    const void* x   = d_in[0];
    const void* W0  = d_in[1];
    const void* al0 = d_in[2];
    const void* ar0 = d_in[3];
    const void* W1  = d_in[4];
    const void* al1 = d_in[5];
    const void* ar1 = d_in[6];
    const void* W2  = d_in[7];
    const void* al2 = d_in[8];
    const void* ar2 = d_in[9];
    const int* src  = (const int*)d_in[10];
    const int* dst  = (const int*)d_in[11];
    const int E = in_sizes[10];
    const int N = NN;

    bf16* fs    = (bf16*)d_ws;                    // N*192 bf16
    bf16* hb16  = fs + (size_t)N * 192;           // N*128 bf16
    float* hbuf = (float*)(hb16 + (size_t)N * 128); // N*192 f32
    float* el   = hbuf + (size_t)N * 192;         // N*4
    float* er   = el + (size_t)N * H;             // N*4
    int* rowptr = (int*)(er + (size_t)N * H);     // N+1
    int* cur    = rowptr + (N + 1);               // N
    int* col    = cur + N;                        // E
    int* bsum   = col + E;                        // 256
    int* boff   = bsum + 256;                     // 256
    int* flag   = boff + 256;                     // 1

    const int gN = (N + 255) / 256;               // 196 blocks
    const int gE = (E + 255) / 256;
    const int gG = (N + 63) / 64;                 // 782 gemm blocks

    detect_k<<<1, 256, 0, stream>>>(x, flag);

    // CSR build (graph identical for all 3 layers)
    zero_i_k<<<gN, 256, 0, stream>>>(cur, N);
    deg_k<<<gE, 256, 0, stream>>>(dst, cur, E);
    scan1_k<<<gN, 256, 0, stream>>>(cur, rowptr, bsum, N);
    scan2_k<<<1, 256, 0, stream>>>(bsum, boff, gN);
    scan3_k<<<gN, 256, 0, stream>>>(rowptr, boff, N, E);
    zero_i_k<<<gN, 256, 0, stream>>>(cur, N);
    fill_k<<<gE, 256, 0, stream>>>(src, dst, rowptr, cur, col, E);

    // ---------------- Layer 0: Fin=100, M=S=128, D=32 ----------------
    gemm_k<100, 128, 128, 32, 0><<<gG, 256, 0, stream>>>(
        x, W0, al0, ar0, fs, el, er, flag, N);
    agg_k<32, 128, 16, 256, true, true><<<N, 256, 0, stream>>>(
        el, er, fs, rowptr, col, hb16);

    // ---------------- Layer 1: Fin=128, M=S=128, D=32 ----------------
    gemm_k<128, 128, 128, 32, 1><<<gG, 256, 0, stream>>>(
        hb16, W1, al1, ar1, fs, el, er, flag, N);
    agg_k<32, 128, 16, 256, true, true><<<N, 256, 0, stream>>>(
        el, er, fs, rowptr, col, hb16);

    // ---------------- Layer 2: Fin=128, M=188, S=192, D=47 ----------------
    gemm_k<128, 188, 192, 47, 1><<<gG, 256, 0, stream>>>(
        hb16, W2, al2, ar2, fs, el, er, flag, N);
    agg_k<47, 192, 24, 192, false, false><<<N, 192, 0, stream>>>(
        el, er, fs, rowptr, col, hbuf);

    final_k<<<N, 64, 0, stream>>>(hbuf, d_out, flag, N);
}